// Round 8
// baseline (53.718 us; speedup 1.0000x reference)
//
#include <hip/hip_runtime.h>

// Bidirectional Chamfer loss, fused:
//   out = 1e-4 * ( sum_n min_m |shape[b,n]-skel[b,m]|^2
//                + sum_m min_n |skel[b,m]-shape[b,n]|^2 )
//
// R8: single change vs R7 — fuse final_kernel into reduce_kernel with a
// last-block ticket (saves one dispatch gap + 1-block tail kernel).
// Chamfer identical to R7 (QPT=8, CHUNK=64, min3 pairing, 3.5 VALU/pair).
// Determinism: last block sums psum in a fixed-order tree; agent-scope
// atomic loads make cross-XCD partials visible.

#define CHUNK  64     // targets per block tile (1 KB in LDS)
#define QPT    8      // query points per thread
#define BIGF   3.4e38f

// ws layout (floats):
//  dir1 partials [b][ch][q] : 4 x 32 x 8192 = 1,048,576
//  dir2 partials [b][ch][q] : 4 x 128 x 2048 = 1,048,576 (at P2_OFF)
//  psum: RBLOCKS floats at PSUM_OFF; ticket counter (uint) at PSUM_OFF+1024.
#define P2_OFF   1048576
#define PSUM_OFF 2097152
#define RBLOCKS  640

__global__ __launch_bounds__(256) void chamfer_kernel(
    const float* __restrict__ shape,  // [4, 8192, 3]
    const float* __restrict__ skel,   // [4, 2048, 3]
    float* __restrict__ pw)           // partial mins (+ psum/counter tail)
{
    const int b   = blockIdx.y;
    const int tid = threadIdx.x;

    // Zero the reduce ticket counter once per call (stream-ordered:
    // reduce_kernel only starts after this kernel fully completes).
    if (blockIdx.x == 0 && b == 0 && tid == 0)
        ((unsigned int*)pw)[PSUM_OFF + 1024] = 0u;

    // 256 tiles/batch: dir1 = 4 qb x 32 ch, dir2 = 1 qb x 128 ch.
    const float* q; const float* t; float* pbase;
    int nq, mt, qb, ch;
    int x = blockIdx.x;
    if (x < 128) {                    // dir1: shape -> skel
        q = shape; t = skel; nq = 8192; mt = 2048;
        qb = x >> 5; ch = x & 31;
        pbase = pw + ((size_t)b * 32 + ch) * 8192;
    } else {                          // dir2: skel -> shape
        x -= 128;
        q = skel; t = shape; nq = 2048; mt = 8192;
        qb = 0; ch = x;
        pbase = pw + P2_OFF + ((size_t)b * 128 + ch) * 2048;
    }

    __shared__ float4 lds[CHUNK];

    // Stage CHUNK targets as (x, y, z, |t|^2).
    if (tid < CHUNK) {
        const float* tb = t + ((size_t)b * mt + ch * CHUNK) * 3;
        float tx = tb[tid * 3 + 0], ty = tb[tid * 3 + 1], tz = tb[tid * 3 + 2];
        lds[tid] = make_float4(tx, ty, tz, tx * tx + ty * ty + tz * tz);
    }

    // My QPT query points: precompute -2q and |q|^2.
    const int q0 = qb * 2048 + tid;               // queries q0 + k*256
    const float* qp = q + ((size_t)b * nq + q0) * 3;
    float nqx[QPT], nqy[QPT], nqz[QPT], qsq[QPT], mn[QPT];
    #pragma unroll
    for (int k = 0; k < QPT; ++k) {
        float xq = qp[k * 768 + 0];               // 768 = 256 pts * 3
        float yq = qp[k * 768 + 1];
        float zq = qp[k * 768 + 2];
        nqx[k] = -2.0f * xq; nqy[k] = -2.0f * yq; nqz[k] = -2.0f * zq;
        qsq[k] = xq * xq + yq * yq + zq * zq;
        mn[k]  = BIGF;
    }

    __syncthreads();

    // 3.5 VALU/pair: per 2 targets & query -> 6 FMA + 1 v_min3_f32.
    #pragma unroll 4
    for (int j = 0; j < CHUNK; j += 2) {
        float4 ta = lds[j + 0];                   // broadcast: conflict-free
        float4 tb = lds[j + 1];
        #pragma unroll
        for (int k = 0; k < QPT; ++k) {
            float e0 = fmaf(nqx[k], ta.x,
                       fmaf(nqy[k], ta.y,
                       fmaf(nqz[k], ta.z, ta.w)));
            float e1 = fmaf(nqx[k], tb.x,
                       fmaf(nqy[k], tb.y,
                       fmaf(nqz[k], tb.z, tb.w)));
            mn[k] = fminf(fminf(mn[k], e0), e1);  // v_min3_f32
        }
    }

    // One coalesced store per (query, chunk) partial — no atomics.
    #pragma unroll
    for (int k = 0; k < QPT; ++k)
        pbase[q0 + k * 256] = qsq[k] + mn[k];
}

// 640 blocks: 64 queries/block, 4 lanes per query split over chunks.
// Blocks 0..511 = dir1 (32 chunks), 512..639 = dir2 (128 chunks).
// Last block (ticket) sums the 640 psum entries (fixed order) -> out.
__global__ __launch_bounds__(256) void reduce_kernel(
    float* __restrict__ pw, float* __restrict__ out)
{
    const int blk = blockIdx.x, tid = threadIdx.x;
    const int sub = tid & 3, qi = tid >> 2;       // 4 lanes per query
    float* psum = pw + PSUM_OFF;
    unsigned int* counter = (unsigned int*)pw + PSUM_OFF + 1024;

    float m = BIGF;
    if (blk < 512) {                              // dir1: 8 loads/lane
        const int b  = blk >> 7;
        const int ql = ((blk & 127) << 6) + qi;
        const float* p = pw + (size_t)b * 32 * 8192 + ql;
        #pragma unroll
        for (int i = 0; i < 8; ++i)
            m = fminf(m, p[(sub * 8 + i) * 8192]);
    } else {                                      // dir2: 32 loads/lane
        const int z  = blk - 512;
        const int b  = z >> 5;
        const int ql = ((z & 31) << 6) + qi;
        const float* p = pw + P2_OFF + (size_t)b * 128 * 2048 + ql;
        #pragma unroll
        for (int i = 0; i < 32; ++i)
            m = fminf(m, p[(sub * 32 + i) * 2048]);
    }

    // Min across the 4-lane group, clamp, keep one copy.
    m = fminf(m, __shfl_xor(m, 1));
    m = fminf(m, __shfl_xor(m, 2));
    float s = (sub == 0) ? fmaxf(m, 0.0f) : 0.0f;

    // Wave + block sum.
    #pragma unroll
    for (int off = 32; off > 0; off >>= 1)
        s += __shfl_down(s, off);

    __shared__ float wsum[4];
    __shared__ bool  sLast;
    const int lane = tid & 63, w = tid >> 6;
    if (lane == 0) wsum[w] = s;
    __syncthreads();

    if (tid == 0) {
        float tot = (wsum[0] + wsum[1]) + (wsum[2] + wsum[3]);
        __hip_atomic_store(&psum[blk], tot, __ATOMIC_RELEASE,
                           __HIP_MEMORY_SCOPE_AGENT);
        __threadfence();
        unsigned int t = __hip_atomic_fetch_add(counter, 1u, __ATOMIC_ACQ_REL,
                                                __HIP_MEMORY_SCOPE_AGENT);
        sLast = (t == RBLOCKS - 1);
    }
    __syncthreads();

    if (sLast) {
        __threadfence();                          // acquire all psum stores
        // Agent-scope loads; fixed-order tree => bitwise deterministic.
        float s2 = __hip_atomic_load(&psum[tid], __ATOMIC_RELAXED,
                                     __HIP_MEMORY_SCOPE_AGENT)
                 + __hip_atomic_load(&psum[tid + 256], __ATOMIC_RELAXED,
                                     __HIP_MEMORY_SCOPE_AGENT);
        if (tid < 128)
            s2 += __hip_atomic_load(&psum[tid + 512], __ATOMIC_RELAXED,
                                    __HIP_MEMORY_SCOPE_AGENT);

        #pragma unroll
        for (int off = 32; off > 0; off >>= 1)
            s2 += __shfl_down(s2, off);
        if (lane == 0) wsum[w] = s2;
        __syncthreads();
        if (tid == 0)
            out[0] = ((wsum[0] + wsum[1]) + (wsum[2] + wsum[3])) * 1.0e-4f;
    }
}

extern "C" void kernel_launch(void* const* d_in, const int* in_sizes, int n_in,
                              void* d_out, int out_size, void* d_ws, size_t ws_size,
                              hipStream_t stream) {
    const float* shape = (const float*)d_in[0];   // [4, 8192, 3]
    const float* skel  = (const float*)d_in[1];   // [4, 2048, 3]
    float* out         = (float*)d_out;           // scalar f32
    float* pw          = (float*)d_ws;

    // 256 tiles/batch x 4 batches = 1024 blocks (4/CU, 4 waves/SIMD).
    chamfer_kernel<<<dim3(256, 4), 256, 0, stream>>>(shape, skel, pw);

    // 640 blocks; the last one finalizes the scalar output.
    reduce_kernel<<<RBLOCKS, 256, 0, stream>>>(pw, out);
}

// Round 9
// 29.032 us; speedup vs baseline: 1.8503x; 1.8503x over previous
//
#include <hip/hip_runtime.h>

// Bidirectional Chamfer loss, fused:
//   out = 1e-4 * ( sum_n min_m |shape[b,n]-skel[b,m]|^2
//                + sum_m min_n |skel[b,m]-shape[b,n]|^2 )
//
// R9: R8's ticket+fence fusion cost +29 us (device-scope __threadfence =
// L2 writeback x640 blocks). Revert to R7 structure; drop final_kernel by
// ending reduce with ONE relaxed atomicAdd(out, tot*1e-4) per block (no
// fence, no read-back). out[0] zeroed by chamfer block (0,0) each call
// (stream-ordered before reduce). 2 dispatches total.

#define CHUNK  64     // targets per block tile (1 KB in LDS)
#define QPT    8      // query points per thread
#define BIGF   3.4e38f

// ws layout (floats):
//  dir1 partials [b][ch][q] : 4 x 32 x 8192 = 1,048,576
//  dir2 partials [b][ch][q] : 4 x 128 x 2048 = 1,048,576 (at P2_OFF)
#define P2_OFF   1048576
#define RBLOCKS  640

__global__ __launch_bounds__(256) void chamfer_kernel(
    const float* __restrict__ shape,  // [4, 8192, 3]
    const float* __restrict__ skel,   // [4, 2048, 3]
    float* __restrict__ pw,           // partial mins
    float* __restrict__ out)          // scalar output (zeroed here)
{
    const int b   = blockIdx.y;
    const int tid = threadIdx.x;

    // Zero the output accumulator once per call (stream-ordered: the
    // reduce kernel only starts after this kernel fully completes).
    if (blockIdx.x == 0 && b == 0 && tid == 0)
        out[0] = 0.0f;

    // 256 tiles/batch: dir1 = 4 qb x 32 ch, dir2 = 1 qb x 128 ch.
    const float* q; const float* t; float* pbase;
    int nq, mt, qb, ch;
    int x = blockIdx.x;
    if (x < 128) {                    // dir1: shape -> skel
        q = shape; t = skel; nq = 8192; mt = 2048;
        qb = x >> 5; ch = x & 31;
        pbase = pw + ((size_t)b * 32 + ch) * 8192;
    } else {                          // dir2: skel -> shape
        x -= 128;
        q = skel; t = shape; nq = 2048; mt = 8192;
        qb = 0; ch = x;
        pbase = pw + P2_OFF + ((size_t)b * 128 + ch) * 2048;
    }

    __shared__ float4 lds[CHUNK];

    // Stage CHUNK targets as (x, y, z, |t|^2).
    if (tid < CHUNK) {
        const float* tb = t + ((size_t)b * mt + ch * CHUNK) * 3;
        float tx = tb[tid * 3 + 0], ty = tb[tid * 3 + 1], tz = tb[tid * 3 + 2];
        lds[tid] = make_float4(tx, ty, tz, tx * tx + ty * ty + tz * tz);
    }

    // My QPT query points: precompute -2q and |q|^2.
    const int q0 = qb * 2048 + tid;               // queries q0 + k*256
    const float* qp = q + ((size_t)b * nq + q0) * 3;
    float nqx[QPT], nqy[QPT], nqz[QPT], qsq[QPT], mn[QPT];
    #pragma unroll
    for (int k = 0; k < QPT; ++k) {
        float xq = qp[k * 768 + 0];               // 768 = 256 pts * 3
        float yq = qp[k * 768 + 1];
        float zq = qp[k * 768 + 2];
        nqx[k] = -2.0f * xq; nqy[k] = -2.0f * yq; nqz[k] = -2.0f * zq;
        qsq[k] = xq * xq + yq * yq + zq * zq;
        mn[k]  = BIGF;
    }

    __syncthreads();

    // 3.5 VALU/pair: per 2 targets & query -> 6 FMA + 1 v_min3_f32.
    #pragma unroll 4
    for (int j = 0; j < CHUNK; j += 2) {
        float4 ta = lds[j + 0];                   // broadcast: conflict-free
        float4 tb = lds[j + 1];
        #pragma unroll
        for (int k = 0; k < QPT; ++k) {
            float e0 = fmaf(nqx[k], ta.x,
                       fmaf(nqy[k], ta.y,
                       fmaf(nqz[k], ta.z, ta.w)));
            float e1 = fmaf(nqx[k], tb.x,
                       fmaf(nqy[k], tb.y,
                       fmaf(nqz[k], tb.z, tb.w)));
            mn[k] = fminf(fminf(mn[k], e0), e1);  // v_min3_f32
        }
    }

    // One coalesced store per (query, chunk) partial — no atomics.
    #pragma unroll
    for (int k = 0; k < QPT; ++k)
        pbase[q0 + k * 256] = qsq[k] + mn[k];
}

// 640 blocks: 64 queries/block, 4 lanes per query split over chunks.
// Blocks 0..511 = dir1 (32 chunks), 512..639 = dir2 (128 chunks).
// Each block contributes its scaled sum via one relaxed atomicAdd.
__global__ __launch_bounds__(256) void reduce_kernel(
    const float* __restrict__ pw, float* __restrict__ out)
{
    const int blk = blockIdx.x, tid = threadIdx.x;
    const int sub = tid & 3, qi = tid >> 2;       // 4 lanes per query

    float m = BIGF;
    if (blk < 512) {                              // dir1: 8 loads/lane
        const int b  = blk >> 7;
        const int ql = ((blk & 127) << 6) + qi;
        const float* p = pw + (size_t)b * 32 * 8192 + ql;
        #pragma unroll
        for (int i = 0; i < 8; ++i)
            m = fminf(m, p[(sub * 8 + i) * 8192]);
    } else {                                      // dir2: 32 loads/lane
        const int z  = blk - 512;
        const int b  = z >> 5;
        const int ql = ((z & 31) << 6) + qi;
        const float* p = pw + P2_OFF + (size_t)b * 128 * 2048 + ql;
        #pragma unroll
        for (int i = 0; i < 32; ++i)
            m = fminf(m, p[(sub * 32 + i) * 2048]);
    }

    // Min across the 4-lane group, clamp, keep one copy.
    m = fminf(m, __shfl_xor(m, 1));
    m = fminf(m, __shfl_xor(m, 2));
    float s = (sub == 0) ? fmaxf(m, 0.0f) : 0.0f;

    // Wave + block sum.
    #pragma unroll
    for (int off = 32; off > 0; off >>= 1)
        s += __shfl_down(s, off);

    __shared__ float wsum[4];
    const int lane = tid & 63, w = tid >> 6;
    if (lane == 0) wsum[w] = s;
    __syncthreads();

    if (tid == 0) {
        float tot = (wsum[0] + wsum[1]) + (wsum[2] + wsum[3]);
        atomicAdd(out, tot * 1.0e-4f);            // fire-and-forget, no fence
    }
}

extern "C" void kernel_launch(void* const* d_in, const int* in_sizes, int n_in,
                              void* d_out, int out_size, void* d_ws, size_t ws_size,
                              hipStream_t stream) {
    const float* shape = (const float*)d_in[0];   // [4, 8192, 3]
    const float* skel  = (const float*)d_in[1];   // [4, 2048, 3]
    float* out         = (float*)d_out;           // scalar f32
    float* pw          = (float*)d_ws;

    // 256 tiles/batch x 4 batches = 1024 blocks (4/CU, 4 waves/SIMD).
    chamfer_kernel<<<dim3(256, 4), 256, 0, stream>>>(shape, skel, pw, out);

    // 640 blocks; each adds its scaled partial to out[0].
    reduce_kernel<<<RBLOCKS, 256, 0, stream>>>(pw, out);
}

// Round 10
// 24.300 us; speedup vs baseline: 2.2106x; 1.1947x over previous
//
#include <hip/hip_runtime.h>

// Bidirectional Chamfer loss, fused:
//   out = 1e-4 * ( sum_n min_m |shape[b,n]-skel[b,m]|^2
//                + sum_m min_n |skel[b,m]-shape[b,n]|^2 )
//
// R10: base = R7 (best: 24.6us; R8 fence-fusion +29, R9 atomic-tail +4.4
// both rejected). Single change: software-pipeline the chamfer inner loop.
// Evidence: R2/R3 chamfer matched its LDS-issue model (41us) => dispatch
// overhead is small and R7's chamfer runs ~18us vs a 6us VALU floor.
// Theory: per-iteration ds_read -> lgkmcnt -> VALU exposes ~120cyc LDS
// latency. Fix: prefetch next 4 targets into regs while processing the
// current 4 (~224 VALU cyc of cover).

#define CHUNK  64     // targets per block tile (1 KB in LDS)
#define QPT    8      // query points per thread
#define BIGF   3.4e38f

// ws layout (floats):
//  dir1 partials [b][ch][q] : 4 x 32 x 8192 = 1,048,576
//  dir2 partials [b][ch][q] : 4 x 128 x 2048 = 1,048,576 (at P2_OFF)
//  psum: RBLOCKS floats at PSUM_OFF
#define P2_OFF   1048576
#define PSUM_OFF 2097152
#define RBLOCKS  640

// Process 4 staged targets against all QPT queries:
// per query: 12 FMA + 2 v_min3_f32.
#define PROC4(p0, p1, p2, p3)                                              \
    _Pragma("unroll")                                                      \
    for (int k = 0; k < QPT; ++k) {                                        \
        float e0 = fmaf(nqx[k], p0.x,                                      \
                   fmaf(nqy[k], p0.y, fmaf(nqz[k], p0.z, p0.w)));          \
        float e1 = fmaf(nqx[k], p1.x,                                      \
                   fmaf(nqy[k], p1.y, fmaf(nqz[k], p1.z, p1.w)));          \
        float e2 = fmaf(nqx[k], p2.x,                                      \
                   fmaf(nqy[k], p2.y, fmaf(nqz[k], p2.z, p2.w)));          \
        float e3 = fmaf(nqx[k], p3.x,                                      \
                   fmaf(nqy[k], p3.y, fmaf(nqz[k], p3.z, p3.w)));          \
        mn[k] = fminf(fminf(mn[k], e0), e1);                               \
        mn[k] = fminf(fminf(mn[k], e2), e3);                               \
    }

__global__ __launch_bounds__(256) void chamfer_kernel(
    const float* __restrict__ shape,  // [4, 8192, 3]
    const float* __restrict__ skel,   // [4, 2048, 3]
    float* __restrict__ pw)           // partial mins
{
    const int b   = blockIdx.y;
    const int tid = threadIdx.x;

    // 256 tiles/batch: dir1 = 4 qb x 32 ch, dir2 = 1 qb x 128 ch.
    const float* q; const float* t; float* pbase;
    int nq, mt, qb, ch;
    int x = blockIdx.x;
    if (x < 128) {                    // dir1: shape -> skel
        q = shape; t = skel; nq = 8192; mt = 2048;
        qb = x >> 5; ch = x & 31;
        pbase = pw + ((size_t)b * 32 + ch) * 8192;
    } else {                          // dir2: skel -> shape
        x -= 128;
        q = skel; t = shape; nq = 2048; mt = 8192;
        qb = 0; ch = x;
        pbase = pw + P2_OFF + ((size_t)b * 128 + ch) * 2048;
    }

    __shared__ float4 lds[CHUNK];

    // Stage CHUNK targets as (x, y, z, |t|^2).
    if (tid < CHUNK) {
        const float* tb = t + ((size_t)b * mt + ch * CHUNK) * 3;
        float tx = tb[tid * 3 + 0], ty = tb[tid * 3 + 1], tz = tb[tid * 3 + 2];
        lds[tid] = make_float4(tx, ty, tz, tx * tx + ty * ty + tz * tz);
    }

    // My QPT query points: precompute -2q and |q|^2.
    const int q0 = qb * 2048 + tid;               // queries q0 + k*256
    const float* qp = q + ((size_t)b * nq + q0) * 3;
    float nqx[QPT], nqy[QPT], nqz[QPT], qsq[QPT], mn[QPT];
    #pragma unroll
    for (int k = 0; k < QPT; ++k) {
        float xq = qp[k * 768 + 0];               // 768 = 256 pts * 3
        float yq = qp[k * 768 + 1];
        float zq = qp[k * 768 + 2];
        nqx[k] = -2.0f * xq; nqy[k] = -2.0f * yq; nqz[k] = -2.0f * zq;
        qsq[k] = xq * xq + yq * yq + zq * zq;
        mn[k]  = BIGF;
    }

    __syncthreads();

    // Software-pipelined: prefetch next 4 targets while processing 4.
    float4 t0 = lds[0], t1 = lds[1], t2 = lds[2], t3 = lds[3];
    #pragma unroll
    for (int j = 0; j < CHUNK - 4; j += 4) {
        float4 n0 = lds[j + 4], n1 = lds[j + 5];
        float4 n2 = lds[j + 6], n3 = lds[j + 7];
        PROC4(t0, t1, t2, t3);
        t0 = n0; t1 = n1; t2 = n2; t3 = n3;
    }
    PROC4(t0, t1, t2, t3);

    // One coalesced store per (query, chunk) partial — no atomics.
    #pragma unroll
    for (int k = 0; k < QPT; ++k)
        pbase[q0 + k * 256] = qsq[k] + mn[k];
}

// 640 blocks: 64 queries/block, 4 lanes per query split over chunks.
// Blocks 0..511 = dir1 (32 chunks), 512..639 = dir2 (128 chunks).
__global__ __launch_bounds__(256) void reduce_kernel(
    const float* __restrict__ pw, float* __restrict__ psum)
{
    const int blk = blockIdx.x, tid = threadIdx.x;
    const int sub = tid & 3, qi = tid >> 2;       // 4 lanes per query

    float m = BIGF;
    if (blk < 512) {                              // dir1: 8 loads/lane
        const int b  = blk >> 7;
        const int ql = ((blk & 127) << 6) + qi;
        const float* p = pw + (size_t)b * 32 * 8192 + ql;
        #pragma unroll
        for (int i = 0; i < 8; ++i)
            m = fminf(m, p[(sub * 8 + i) * 8192]);
    } else {                                      // dir2: 32 loads/lane
        const int z  = blk - 512;
        const int b  = z >> 5;
        const int ql = ((z & 31) << 6) + qi;
        const float* p = pw + P2_OFF + (size_t)b * 128 * 2048 + ql;
        #pragma unroll
        for (int i = 0; i < 32; ++i)
            m = fminf(m, p[(sub * 32 + i) * 2048]);
    }

    // Min across the 4-lane group, clamp, keep one copy.
    m = fminf(m, __shfl_xor(m, 1));
    m = fminf(m, __shfl_xor(m, 2));
    float s = (sub == 0) ? fmaxf(m, 0.0f) : 0.0f;

    // Wave + block sum.
    #pragma unroll
    for (int off = 32; off > 0; off >>= 1)
        s += __shfl_down(s, off);

    __shared__ float wsum[4];
    const int lane = tid & 63, w = tid >> 6;
    if (lane == 0) wsum[w] = s;
    __syncthreads();
    if (tid == 0) psum[blk] = (wsum[0] + wsum[1]) + (wsum[2] + wsum[3]);
}

__global__ __launch_bounds__(256) void final_kernel(
    const float* __restrict__ psum, float* __restrict__ out)
{
    float s = psum[threadIdx.x] + psum[threadIdx.x + 256];
    if (threadIdx.x < 128) s += psum[threadIdx.x + 512];

    #pragma unroll
    for (int off = 32; off > 0; off >>= 1)
        s += __shfl_down(s, off);

    __shared__ float wsum[4];
    const int lane = threadIdx.x & 63, w = threadIdx.x >> 6;
    if (lane == 0) wsum[w] = s;
    __syncthreads();
    if (threadIdx.x == 0)
        out[0] = ((wsum[0] + wsum[1]) + (wsum[2] + wsum[3])) * 1.0e-4f;
}

extern "C" void kernel_launch(void* const* d_in, const int* in_sizes, int n_in,
                              void* d_out, int out_size, void* d_ws, size_t ws_size,
                              hipStream_t stream) {
    const float* shape = (const float*)d_in[0];   // [4, 8192, 3]
    const float* skel  = (const float*)d_in[1];   // [4, 2048, 3]
    float* out         = (float*)d_out;           // scalar f32
    float* pw          = (float*)d_ws;

    // 256 tiles/batch x 4 batches = 1024 blocks (4/CU, 4 waves/SIMD).
    chamfer_kernel<<<dim3(256, 4), 256, 0, stream>>>(shape, skel, pw);

    // 640 blocks, then tiny deterministic final sum.
    reduce_kernel<<<RBLOCKS, 256, 0, stream>>>(pw, pw + PSUM_OFF);
    final_kernel<<<1, 256, 0, stream>>>(pw + PSUM_OFF, out);
}